// Round 1
// baseline (242.878 us; speedup 1.0000x reference)
//
#include <hip/hip_runtime.h>
#include <hip/hip_bf16.h>

#define NF 50
#define NCARD 10000
#define FD 64
#define NPAIR 1225        // 50*49/2
#define NPAIR_PAD 1232    // 77*16
#define NTILE 77
#define FSTRIDE 68        // 64 + 4 pad: bank group = 4*i mod 32 -> ~2-way conflicts (free)

typedef short bf16x8 __attribute__((ext_vector_type(8)));
typedef float f32x4 __attribute__((ext_vector_type(4)));

__device__ inline short f2bf(float f) {
    // round-to-nearest-even f32 -> bf16 (values here are small/normal; no NaN handling needed)
    union { float f; unsigned u; } v; v.f = f;
    unsigned r = v.u + 0x7fffu + ((v.u >> 16) & 1u);
    return (short)(r >> 16);
}

__global__ __launch_bounds__(256) void afm_kernel(
    const int* __restrict__ x,
    const float* __restrict__ emb,
    const float* __restrict__ W1,
    const float* __restrict__ b1,
    const float* __restrict__ w2,
    const float* __restrict__ lin_w,
    const float* __restrict__ lin_b,
    float* __restrict__ out)
{
    __shared__ __align__(16) float fac[NF * FSTRIDE]; // 13600 B
    __shared__ float plog[NPAIR_PAD];                 // 4928 B
    __shared__ float pis[NPAIR_PAD];                  // 4928 B
    __shared__ unsigned char pi8[NPAIR_PAD];
    __shared__ unsigned char pj8[NPAIR_PAD];
    __shared__ float s_red[8];
    __shared__ float s_red2[8];
    __shared__ float s_linear;

    const int b    = blockIdx.x;
    const int tid  = threadIdx.x;
    const int lane = tid & 63;
    const int wid  = tid >> 6;
    const int n16  = lane & 15;
    const int quad = lane >> 4;

    if (tid == 0) s_linear = 0.f;
    __syncthreads();

    // ---- stage factor rows into LDS (coalesced float4) + linear term + pair tables ----
    const int* xrow = x + b * NF;
    for (int t = tid; t < NF * 16; t += 256) {
        int f = t >> 4, q = t & 15;
        int gid = xrow[f] + f * NCARD;
        const float4 v = *(const float4*)(emb + (size_t)gid * FD + (q << 2));
        *(float4*)(&fac[f * FSTRIDE + (q << 2)]) = v;
    }
    if (tid < NF) {
        int gid = xrow[tid] + tid * NCARD;
        atomicAdd(&s_linear, lin_w[gid]);
    }
    for (int p = tid; p < NPAIR_PAD; p += 256) {
        int i = 0, j = 0;
        if (p < NPAIR) {
            float disc = (float)((2 * NF - 1) * (2 * NF - 1) - 8 * p);
            i = (int)(((float)(2 * NF - 1) - sqrtf(disc)) * 0.5f);
            if (i < 0) i = 0;
            if (i > NF - 2) i = NF - 2;
            // base(i) = i*(NF-1) - i*(i-1)/2 ; fix up float sqrt
            while (i + 1 <= NF - 2 && (i + 1) * (NF - 1) - ((i + 1) * i) / 2 <= p) ++i;
            while (i > 0 && i * (NF - 1) - (i * (i - 1)) / 2 > p) --i;
            j = p - (i * (NF - 1) - (i * (i - 1)) / 2) + i + 1;
        }
        pi8[p] = (unsigned char)i;
        pj8[p] = (unsigned char)j;
    }

    // ---- per-lane B fragments (W1), b1/w2 slices: B[k][n], k=ks*32+quad*8+j, n=nt*16+n16 ----
    bf16x8 bfrag[4][2];
    float b1v[4], w2v[4];
    #pragma unroll
    for (int nt = 0; nt < 4; ++nt) {
        int a = nt * 16 + n16;
        b1v[nt] = b1[a];
        w2v[nt] = w2[a];
        #pragma unroll
        for (int ks = 0; ks < 2; ++ks) {
            bf16x8 bv;
            #pragma unroll
            for (int jj = 0; jj < 8; ++jj) {
                int k = ks * 32 + quad * 8 + jj;
                bv[jj] = f2bf(W1[k * 64 + a]);
            }
            bfrag[nt][ks] = bv;
        }
    }
    __syncthreads();

    // ---- main loop: each wave takes M-tiles of 16 pairs ----
    for (int t = wid; t < NTILE; t += 4) {
        const int p0 = t * 16;
        const int p  = p0 + n16;            // this lane's pair (A-layout m = lane&15)
        const int fi = pi8[p];
        const int fj = pj8[p];
        const float* fpi = &fac[fi * FSTRIDE];
        const float* fpj = &fac[fj * FSTRIDE];

        float is = 0.f;
        bf16x8 afrag[2];
        #pragma unroll
        for (int ks = 0; ks < 2; ++ks) {
            const int k0 = ks * 32 + quad * 8;   // A-layout k = quad*8+j (+32 for ks=1)
            float4 a0 = *(const float4*)(fpi + k0);
            float4 a1 = *(const float4*)(fpi + k0 + 4);
            float4 c0 = *(const float4*)(fpj + k0);
            float4 c1 = *(const float4*)(fpj + k0 + 4);
            float v0 = a0.x * c0.x, v1 = a0.y * c0.y, v2 = a0.z * c0.z, v3 = a0.w * c0.w;
            float v4 = a1.x * c1.x, v5 = a1.y * c1.y, v6 = a1.z * c1.z, v7 = a1.w * c1.w;
            is += ((v0 + v1) + (v2 + v3)) + ((v4 + v5) + (v6 + v7)); // fp32 inter_sum
            bf16x8 av;
            av[0] = f2bf(v0); av[1] = f2bf(v1); av[2] = f2bf(v2); av[3] = f2bf(v3);
            av[4] = f2bf(v4); av[5] = f2bf(v5); av[6] = f2bf(v6); av[7] = f2bf(v7);
            afrag[ks] = av;
        }

        // H = inter @ W1 over 4 att-tiles; fuse relu/b1/w2 dot in C layout
        float lacc[4] = {0.f, 0.f, 0.f, 0.f};
        #pragma unroll
        for (int nt = 0; nt < 4; ++nt) {
            f32x4 acc = {0.f, 0.f, 0.f, 0.f};
            acc = __builtin_amdgcn_mfma_f32_16x16x32_bf16(afrag[0], bfrag[nt][0], acc, 0, 0, 0);
            acc = __builtin_amdgcn_mfma_f32_16x16x32_bf16(afrag[1], bfrag[nt][1], acc, 0, 0, 0);
            #pragma unroll
            for (int r = 0; r < 4; ++r)
                lacc[r] += fmaxf(acc[r] + b1v[nt], 0.f) * w2v[nt];
        }
        // sum over att dim: reduce across the 16 lanes of each quad (C col = lane&15)
        #pragma unroll
        for (int m = 1; m <= 8; m <<= 1) {
            #pragma unroll
            for (int r = 0; r < 4; ++r) lacc[r] += __shfl_xor(lacc[r], m, 64);
        }
        if (n16 == 0) {
            int prow = p0 + (quad << 2);     // C row = quad*4 + reg
            plog[prow + 0] = lacc[0];
            plog[prow + 1] = lacc[1];
            plog[prow + 2] = lacc[2];
            plog[prow + 3] = lacc[3];
        }
        // inter_sum: lane holds k-slice of pair p; reduce across quads
        is += __shfl_xor(is, 16, 64);
        is += __shfl_xor(is, 32, 64);
        if (lane < 16) pis[p] = is;
    }
    __syncthreads();

    // ---- softmax over 1225 logits + attended + output ----
    float mx = -1e30f;
    for (int p = tid; p < NPAIR; p += 256) mx = fmaxf(mx, plog[p]);
    #pragma unroll
    for (int m = 32; m >= 1; m >>= 1) mx = fmaxf(mx, __shfl_xor(mx, m, 64));
    if (lane == 0) s_red[wid] = mx;
    __syncthreads();
    mx = fmaxf(fmaxf(s_red[0], s_red[1]), fmaxf(s_red[2], s_red[3]));
    __syncthreads();   // protect s_red before reuse

    float se = 0.f, sei = 0.f;
    for (int p = tid; p < NPAIR; p += 256) {
        float e = __expf(plog[p] - mx);
        se  += e;
        sei += e * pis[p];
    }
    #pragma unroll
    for (int m = 32; m >= 1; m >>= 1) {
        se  += __shfl_xor(se, m, 64);
        sei += __shfl_xor(sei, m, 64);
    }
    if (lane == 0) { s_red[wid] = se; s_red2[wid] = sei; }
    __syncthreads();
    if (tid == 0) {
        float tse  = s_red[0] + s_red[1] + s_red[2] + s_red[3];
        float tsei = s_red2[0] + s_red2[1] + s_red2[2] + s_red2[3];
        out[b] = s_linear + lin_b[0] + tsei / tse;
    }
}

extern "C" void kernel_launch(void* const* d_in, const int* in_sizes, int n_in,
                              void* d_out, int out_size, void* d_ws, size_t ws_size,
                              hipStream_t stream) {
    const int*   x     = (const int*)d_in[0];
    const float* emb   = (const float*)d_in[1];
    const float* W1    = (const float*)d_in[2];
    const float* b1    = (const float*)d_in[3];
    const float* w2    = (const float*)d_in[4];
    // d_in[5] = b2 : constant shift on logits, cancels in softmax
    const float* lin_w = (const float*)d_in[6];
    const float* lin_b = (const float*)d_in[7];
    float* out = (float*)d_out;
    const int batch = out_size; // 2048
    afm_kernel<<<batch, 256, 0, stream>>>(x, emb, W1, b1, w2, lin_w, lin_b, out);
}

// Round 2
// 218.929 us; speedup vs baseline: 1.1094x; 1.1094x over previous
//
#include <hip/hip_runtime.h>
#include <hip/hip_bf16.h>

#define NF 50
#define NCARD 10000
#define FD 64
#define NPAIR 1225        // 50*49/2
#define NPAIR_PAD 1232    // 77*16
#define NTILE 77
#define FSH 72            // half-stride per field row = 144 B (non-pow2 to spread banks)

typedef _Float16 h16x8 __attribute__((ext_vector_type(8)));
typedef float f32x4 __attribute__((ext_vector_type(4)));

__global__ __launch_bounds__(256) void afm_kernel(
    const int* __restrict__ x,
    const float* __restrict__ emb,
    const float* __restrict__ W1,
    const float* __restrict__ b1,
    const float* __restrict__ w2,
    const float* __restrict__ lin_w,
    const float* __restrict__ lin_b,
    float* __restrict__ out)
{
    __shared__ __align__(16) _Float16 fach[NF * FSH]; // 7200 B
    __shared__ float plog[NPAIR_PAD];                 // 4928 B
    __shared__ float pis[NPAIR_PAD];                  // 4928 B
    __shared__ unsigned poff[NPAIR_PAD];              // 4928 B: fi*144 | (fj*144<<16)
    __shared__ float s_red[8];
    __shared__ float s_red2[8];
    __shared__ float s_linear;

    const int b    = blockIdx.x;
    const int tid  = threadIdx.x;
    const int lane = tid & 63;
    const int wid  = tid >> 6;
    const int n16  = lane & 15;
    const int quad = lane >> 4;

    if (tid == 0) s_linear = 0.f;
    __syncthreads();

    // ---- stage factor rows into LDS as f16 (coalesced float4 loads) ----
    const int* xrow = x + b * NF;
    for (int t = tid; t < NF * 8; t += 256) {
        int f = t >> 3, q = t & 7;
        int gid = xrow[f] + f * NCARD;
        const float* src = emb + (size_t)gid * FD + q * 8;
        float4 v0 = *(const float4*)(src);
        float4 v1 = *(const float4*)(src + 4);
        h16x8 h;
        h[0] = (_Float16)v0.x; h[1] = (_Float16)v0.y;
        h[2] = (_Float16)v0.z; h[3] = (_Float16)v0.w;
        h[4] = (_Float16)v1.x; h[5] = (_Float16)v1.y;
        h[6] = (_Float16)v1.z; h[7] = (_Float16)v1.w;
        *(h16x8*)(fach + f * FSH + q * 8) = h;
    }
    if (tid < NF) {
        int gid = xrow[tid] + tid * NCARD;
        atomicAdd(&s_linear, lin_w[gid]);
    }
    // ---- pair offset table ----
    for (int p = tid; p < NPAIR_PAD; p += 256) {
        int i = 0, j = 0;
        if (p < NPAIR) {
            float disc = (float)((2 * NF - 1) * (2 * NF - 1) - 8 * p);
            i = (int)(((float)(2 * NF - 1) - sqrtf(disc)) * 0.5f);
            if (i < 0) i = 0;
            if (i > NF - 2) i = NF - 2;
            while (i + 1 <= NF - 2 && (i + 1) * (NF - 1) - ((i + 1) * i) / 2 <= p) ++i;
            while (i > 0 && i * (NF - 1) - (i * (i - 1)) / 2 > p) --i;
            j = p - (i * (NF - 1) - (i * (i - 1)) / 2) + i + 1;
        }
        poff[p] = (unsigned)(i * (FSH * 2)) | ((unsigned)(j * (FSH * 2)) << 16);
    }

    // ---- W1^T as MFMA A-operand (att = M): A[m=mt*16+n16][k=ks*32+quad*8+jj] = W1[k*64+m]
    h16x8 afragW[4][2];
    #pragma unroll
    for (int mt = 0; mt < 4; ++mt) {
        int a = mt * 16 + n16;
        #pragma unroll
        for (int ks = 0; ks < 2; ++ks) {
            h16x8 av;
            #pragma unroll
            for (int jj = 0; jj < 8; ++jj) {
                int k = ks * 32 + quad * 8 + jj;
                av[jj] = (_Float16)W1[k * 64 + a];
            }
            afragW[mt][ks] = av;
        }
    }
    // ones-row A fragment: row 0 of a virtual 5th M-tile -> C[0][n] = sum_k B[k][n]
    h16x8 aones;
    {
        _Float16 o = (n16 == 0) ? (_Float16)1.0f : (_Float16)0.0f;
        #pragma unroll
        for (int jj = 0; jj < 8; ++jj) aones[jj] = o;
    }
    // b1 / w2 slices per lane, indexed by C row = mt*16 + quad*4 + r
    f32x4 b1v[4], w2v[4];
    #pragma unroll
    for (int mt = 0; mt < 4; ++mt) {
        const float4 bb = *(const float4*)(b1 + mt * 16 + quad * 4);
        const float4 ww = *(const float4*)(w2 + mt * 16 + quad * 4);
        b1v[mt] = (f32x4){bb.x, bb.y, bb.z, bb.w};
        w2v[mt] = (f32x4){ww.x, ww.y, ww.z, ww.w};
    }
    __syncthreads();

    // ---- main loop: each wave takes 16-pair tiles; pairs are the MFMA N dim ----
    const char* fbase = (const char*)fach;
    for (int t = wid; t < NTILE; t += 4) {
        const int p0 = t * 16;
        const unsigned po = poff[p0 + n16];   // this lane's pair (B-layout n = lane&15)
        const char* pbi = fbase + (po & 0xFFFFu) + quad * 16;
        const char* pbj = fbase + (po >> 16) + quad * 16;

        f32x4 acc[4];
        #pragma unroll
        for (int mt = 0; mt < 4; ++mt) acc[mt] = b1v[mt];   // fold b1 into C init
        f32x4 accS = {0.f, 0.f, 0.f, 0.f};

        #pragma unroll
        for (int ks = 0; ks < 2; ++ks) {
            h16x8 fi = *(const h16x8*)(pbi + ks * 64);
            h16x8 fj = *(const h16x8*)(pbj + ks * 64);
            h16x8 pr = fi * fj;                              // 4x v_pk_mul_f16
            #pragma unroll
            for (int mt = 0; mt < 4; ++mt)
                acc[mt] = __builtin_amdgcn_mfma_f32_16x16x32_f16(afragW[mt][ks], pr, acc[mt], 0, 0, 0);
            accS = __builtin_amdgcn_mfma_f32_16x16x32_f16(aones, pr, accS, 0, 0, 0);
        }

        // logit = sum_a relu(h[a]) * w2[a]; rows live in-lane, cols are pairs
        float lacc = 0.f;
        #pragma unroll
        for (int mt = 0; mt < 4; ++mt) {
            #pragma unroll
            for (int r = 0; r < 4; ++r)
                lacc += fmaxf(acc[mt][r], 0.f) * w2v[mt][r];
        }
        lacc += __shfl_xor(lacc, 16, 64);
        lacc += __shfl_xor(lacc, 32, 64);
        if (lane < 16) {
            plog[p0 + lane] = lacc;
            pis[p0 + lane] = accS[0];   // C[0][pair] of ones-tile = inter_sum
        }
    }
    __syncthreads();

    // ---- softmax over 1225 logits + attended + output ----
    float mx = -1e30f;
    for (int p = tid; p < NPAIR; p += 256) mx = fmaxf(mx, plog[p]);
    #pragma unroll
    for (int m = 32; m >= 1; m >>= 1) mx = fmaxf(mx, __shfl_xor(mx, m, 64));
    if (lane == 0) s_red[wid] = mx;
    __syncthreads();
    mx = fmaxf(fmaxf(s_red[0], s_red[1]), fmaxf(s_red[2], s_red[3]));
    __syncthreads();

    float se = 0.f, sei = 0.f;
    for (int p = tid; p < NPAIR; p += 256) {
        float e = __expf(plog[p] - mx);
        se  += e;
        sei += e * pis[p];
    }
    #pragma unroll
    for (int m = 32; m >= 1; m >>= 1) {
        se  += __shfl_xor(se, m, 64);
        sei += __shfl_xor(sei, m, 64);
    }
    if (lane == 0) { s_red[wid] = se; s_red2[wid] = sei; }
    __syncthreads();
    if (tid == 0) {
        float tse  = s_red[0] + s_red[1] + s_red[2] + s_red[3];
        float tsei = s_red2[0] + s_red2[1] + s_red2[2] + s_red2[3];
        out[b] = s_linear + lin_b[0] + tsei / tse;
    }
}

extern "C" void kernel_launch(void* const* d_in, const int* in_sizes, int n_in,
                              void* d_out, int out_size, void* d_ws, size_t ws_size,
                              hipStream_t stream) {
    const int*   x     = (const int*)d_in[0];
    const float* emb   = (const float*)d_in[1];
    const float* W1    = (const float*)d_in[2];
    const float* b1    = (const float*)d_in[3];
    const float* w2    = (const float*)d_in[4];
    // d_in[5] = b2 : constant shift on logits, cancels in softmax
    const float* lin_w = (const float*)d_in[6];
    const float* lin_b = (const float*)d_in[7];
    float* out = (float*)d_out;
    const int batch = out_size; // 2048
    afm_kernel<<<batch, 256, 0, stream>>>(x, emb, W1, b1, w2, lin_w, lin_b, out);
}

// Round 3
// 215.464 us; speedup vs baseline: 1.1272x; 1.0161x over previous
//
#include <hip/hip_runtime.h>
#include <hip/hip_bf16.h>

#define NF 50
#define NCARD 10000
#define FD 64
#define NPAIR 1225        // 50*49/2
#define NPAIR_PAD 1232    // 77*16
#define NTILE 77
#define NB 2              // batch elements per block (one per wave-pair)
#define FROWB 144         // bytes per field row in LDS (72 f16, non-pow2 -> 2-way max)
#define FBATB 7200        // bytes per batch section (50*144)

typedef _Float16 h16x8 __attribute__((ext_vector_type(8)));
typedef float f32x4 __attribute__((ext_vector_type(4)));

// ---------------- pre-kernel: batch-invariant tables into d_ws ----------------
// ws layout: [0,8192) f16 W1 fragments, slot-major: frag[(mt*2+ks)*64 + lane][8]
//            [8192, 8192+4*NPAIR_PAD) unsigned poff: fi*144 | (fj*144 << 16)
__global__ void afm_pre(const float* __restrict__ W1,
                        _Float16* __restrict__ w1f,
                        unsigned* __restrict__ poffg) {
    const int bid = blockIdx.x, tid = threadIdx.x;
    if (bid < 2) {
        const int slot = bid * 4 + (tid >> 6);   // 0..7 = mt*2+ks
        const int lane = tid & 63;
        const int n16 = lane & 15, quad = lane >> 4;
        const int mt = slot >> 1, ks = slot & 1;
        const int a = mt * 16 + n16;
        h16x8 v;
        #pragma unroll
        for (int jj = 0; jj < 8; ++jj) {
            int k = ks * 32 + quad * 8 + jj;
            v[jj] = (_Float16)W1[k * 64 + a];    // A[m=a][k] = W1^T
        }
        *(h16x8*)(w1f + ((size_t)(slot * 64 + lane)) * 8) = v;
    } else {
        int p = (bid - 2) * 256 + tid;
        if (p < NPAIR_PAD) {
            int i = 0, j = 0;
            if (p < NPAIR) {
                float disc = (float)((2 * NF - 1) * (2 * NF - 1) - 8 * p);
                i = (int)(((float)(2 * NF - 1) - sqrtf(disc)) * 0.5f);
                if (i < 0) i = 0;
                if (i > NF - 2) i = NF - 2;
                while (i + 1 <= NF - 2 && (i + 1) * (NF - 1) - ((i + 1) * i) / 2 <= p) ++i;
                while (i > 0 && i * (NF - 1) - (i * (i - 1)) / 2 > p) --i;
                j = p - (i * (NF - 1) - (i * (i - 1)) / 2) + i + 1;
            }
            poffg[p] = (unsigned)(i * FROWB) | ((unsigned)(j * FROWB) << 16);
        }
    }
}

// ---------------- main kernel: 2 batches/block, online softmax in regs --------
__global__ __launch_bounds__(256, 4) void afm_main(
    const int* __restrict__ x,
    const float* __restrict__ emb,
    const float* __restrict__ b1,
    const float* __restrict__ w2,
    const float* __restrict__ lin_w,
    const float* __restrict__ lin_b,
    const _Float16* __restrict__ w1f,
    const unsigned* __restrict__ poffg,
    float* __restrict__ out)
{
    __shared__ __align__(16) _Float16 fach[NB * 50 * 72]; // 14400 B
    __shared__ unsigned poff[NPAIR_PAD];                  // 4928 B
    __shared__ float cmb[4][3];

    const int b0   = blockIdx.x * NB;
    const int tid  = threadIdx.x;
    const int lane = tid & 63;
    const int wid  = tid >> 6;
    const int n16  = lane & 15;
    const int quad = lane >> 4;

    // ---- stage NB*50 factor rows as f16 + poff table ----
    for (int t = tid; t < NB * 50 * 8; t += 256) {
        int rowid = t >> 3, q = t & 7;
        int bb = (rowid >= 50) ? 1 : 0;
        int f = rowid - bb * 50;
        int gid = x[(b0 + bb) * NF + f] + f * NCARD;
        const float* src = emb + (size_t)gid * FD + q * 8;
        float4 v0 = *(const float4*)(src);
        float4 v1 = *(const float4*)(src + 4);
        h16x8 h;
        h[0] = (_Float16)v0.x; h[1] = (_Float16)v0.y;
        h[2] = (_Float16)v0.z; h[3] = (_Float16)v0.w;
        h[4] = (_Float16)v1.x; h[5] = (_Float16)v1.y;
        h[6] = (_Float16)v1.z; h[7] = (_Float16)v1.w;
        *(h16x8*)(fach + bb * 3600 + f * 72 + q * 8) = h;
    }
    for (int p = tid; p < NPAIR_PAD; p += 256) poff[p] = poffg[p];

    // ---- per-lane constants (register-resident, no LDS dependency) ----
    h16x8 afragW[8];                       // W1^T fragments, [mt*2+ks]
    #pragma unroll
    for (int s = 0; s < 8; ++s)
        afragW[s] = *(const h16x8*)(w1f + ((size_t)(s * 64 + lane)) * 8);
    h16x8 aones;                           // virtual ones-row tile -> inter_sum
    {
        _Float16 o = (n16 == 0) ? (_Float16)1.0f : (_Float16)0.0f;
        #pragma unroll
        for (int jj = 0; jj < 8; ++jj) aones[jj] = o;
    }
    f32x4 b1v[4], w2v[4];                  // C row = mt*16 + quad*4 + r
    #pragma unroll
    for (int mt = 0; mt < 4; ++mt) {
        const float4 bb = *(const float4*)(b1 + mt * 16 + quad * 4);
        const float4 ww = *(const float4*)(w2 + mt * 16 + quad * 4);
        b1v[mt] = (f32x4){bb.x, bb.y, bb.z, bb.w};
        w2v[mt] = (f32x4){ww.x, ww.y, ww.z, ww.w};
    }
    __syncthreads();

    // ---- main loop: wave pair (2w, 2w+1) covers batch w; online softmax ----
    const int mybatch = wid >> 1;
    const char* fb = (const char*)fach + mybatch * FBATB;
    float m = -1e30f, se = 0.f, sei = 0.f;

    for (int t = (wid & 1); t < NTILE; t += 2) {
        const unsigned po = poff[t * 16 + n16];
        const char* pbi = fb + (po & 0xFFFFu) + quad * 16;
        const char* pbj = fb + (po >> 16) + quad * 16;

        h16x8 fi0 = *(const h16x8*)(pbi);
        h16x8 fj0 = *(const h16x8*)(pbj);
        h16x8 fi1 = *(const h16x8*)(pbi + 64);
        h16x8 fj1 = *(const h16x8*)(pbj + 64);
        h16x8 pr0 = fi0 * fj0;                     // 4x v_pk_mul_f16 each
        h16x8 pr1 = fi1 * fj1;

        f32x4 acc[4];
        #pragma unroll
        for (int mt = 0; mt < 4; ++mt) {
            acc[mt] = __builtin_amdgcn_mfma_f32_16x16x32_f16(afragW[mt * 2 + 0], pr0, b1v[mt], 0, 0, 0);
            acc[mt] = __builtin_amdgcn_mfma_f32_16x16x32_f16(afragW[mt * 2 + 1], pr1, acc[mt], 0, 0, 0);
        }
        f32x4 accS = __builtin_amdgcn_mfma_f32_16x16x32_f16(aones, pr0, (f32x4){0.f, 0.f, 0.f, 0.f}, 0, 0, 0);
        accS = __builtin_amdgcn_mfma_f32_16x16x32_f16(aones, pr1, accS, 0, 0, 0);

        float lacc = 0.f;                          // sum_a relu(h)*w2, rows in-lane
        #pragma unroll
        for (int mt = 0; mt < 4; ++mt) {
            #pragma unroll
            for (int r = 0; r < 4; ++r)
                lacc += fmaxf(acc[mt][r], 0.f) * w2v[mt][r];
        }
        lacc += __shfl_xor(lacc, 16, 64);          // reduce over att rows
        lacc += __shfl_xor(lacc, 32, 64);
        float is = __shfl(accS[0], n16, 64);       // inter_sum lives in quad-0 row 0

        if (t * 16 + n16 >= NPAIR) lacc = -1e30f;  // padded pairs (tile 76 only)

        float nm = fmaxf(m, lacc);
        float sc = __expf(m - nm);
        float e  = __expf(lacc - nm);
        se  = se * sc + e;
        sei = sei * sc + e * is;
        m = nm;
    }

    // merge per-lane online states across the 16 pair-residues (quads replicated)
    #pragma unroll
    for (int d = 1; d <= 8; d <<= 1) {
        float m2   = __shfl_xor(m, d, 64);
        float se2  = __shfl_xor(se, d, 64);
        float sei2 = __shfl_xor(sei, d, 64);
        float nm = fmaxf(m, m2);
        float a = __expf(m - nm), bsc = __expf(m2 - nm);
        se  = se * a + se2 * bsc;
        sei = sei * a + sei2 * bsc;
        m = nm;
    }

    // linear term: even wave of each pair gathers lin_w
    float lin = 0.f;
    if ((wid & 1) == 0) {
        if (lane < NF) {
            int gid = x[(b0 + mybatch) * NF + lane] + lane * NCARD;
            lin = lin_w[gid];
        }
        #pragma unroll
        for (int d = 1; d <= 32; d <<= 1) lin += __shfl_xor(lin, d, 64);
    }

    // cross-wave combine (one barrier) + output
    if (lane == 0) { cmb[wid][0] = m; cmb[wid][1] = se; cmb[wid][2] = sei; }
    __syncthreads();
    if ((wid & 1) == 0 && lane == 0) {
        float m2 = cmb[wid + 1][0], se2 = cmb[wid + 1][1], sei2 = cmb[wid + 1][2];
        float nm = fmaxf(m, m2);
        float a = __expf(m - nm), bsc = __expf(m2 - nm);
        float tse  = se * a + se2 * bsc;
        float tsei = sei * a + sei2 * bsc;
        out[b0 + mybatch] = lin + lin_b[0] + tsei / tse;
    }
}

extern "C" void kernel_launch(void* const* d_in, const int* in_sizes, int n_in,
                              void* d_out, int out_size, void* d_ws, size_t ws_size,
                              hipStream_t stream) {
    const int*   x     = (const int*)d_in[0];
    const float* emb   = (const float*)d_in[1];
    const float* W1    = (const float*)d_in[2];
    const float* b1    = (const float*)d_in[3];
    const float* w2    = (const float*)d_in[4];
    // d_in[5] = b2 : constant shift on logits, cancels in softmax
    const float* lin_w = (const float*)d_in[6];
    const float* lin_b = (const float*)d_in[7];
    float* out = (float*)d_out;

    _Float16* w1f   = (_Float16*)d_ws;
    unsigned* poffg = (unsigned*)((char*)d_ws + 8192);

    afm_pre<<<7, 256, 0, stream>>>(W1, w1f, poffg);   // blocks 0-1: W1, 2-6: pairs
    const int batch = out_size; // 2048
    afm_main<<<batch / NB, 256, 0, stream>>>(x, emb, b1, w2, lin_w, lin_b, w1f, poffg, out);
}